// Round 1
// baseline (589.986 us; speedup 1.0000x reference)
//
#include <hip/hip_runtime.h>
#include <hip/hip_bf16.h>

#define BB 4
#define NN 2048
#define DD 1024
#define HH 16

using bf16 = __hip_bfloat16;
typedef __attribute__((ext_vector_type(8))) short bf16x8s;
typedef __attribute__((ext_vector_type(4))) float f32x4;

// ---------------- cast f32 -> bf16 (vectorized x4) ----------------
__global__ void cast_f32_bf16(const float* __restrict__ in, bf16* __restrict__ out, int n) {
  int i = (blockIdx.x * blockDim.x + threadIdx.x) * 4;
  if (i >= n) return;
  float4 v = *reinterpret_cast<const float4*>(in + i);
  ushort4 o;
  bf16 t0 = __float2bfloat16(v.x); o.x = *reinterpret_cast<unsigned short*>(&t0);
  bf16 t1 = __float2bfloat16(v.y); o.y = *reinterpret_cast<unsigned short*>(&t1);
  bf16 t2 = __float2bfloat16(v.z); o.z = *reinterpret_cast<unsigned short*>(&t2);
  bf16 t3 = __float2bfloat16(v.w); o.w = *reinterpret_cast<unsigned short*>(&t3);
  *reinterpret_cast<ushort4*>(out + i) = o;
}

// ---------------- transpose + cast: in[R,C] f32 -> out[C,R] bf16 ----------------
__global__ void transpose_cast(const float* __restrict__ in, bf16* __restrict__ out, int R, int C) {
  __shared__ float t[32][33];
  int c0 = blockIdx.x * 32, r0 = blockIdx.y * 32;
  int tx = threadIdx.x, ty = threadIdx.y;  // block (32,8)
#pragma unroll
  for (int i = 0; i < 4; i++)
    t[ty + i * 8][tx] = in[(size_t)(r0 + ty + i * 8) * C + c0 + tx];
  __syncthreads();
#pragma unroll
  for (int i = 0; i < 4; i++)
    out[(size_t)(c0 + ty + i * 8) * R + r0 + tx] = __float2bfloat16(t[tx][ty + i * 8]);
}

// ---------------- bf16 MFMA GEMM: C[M,Nc] = A[M,K] * BT[Nc,K]^T + bias (+rowadd) ----------------
// 128x128 tile, BK=32, 4 waves (2x2), each wave 64x64 via 4x4 16x16x32 mfma frags.
// LDS rows padded to 56 elems (112B): 16B-aligned, 2-way-max bank pattern on ds_read_b128.
template <int OUT_BF16, int HAS_ROWADD>
__global__ __launch_bounds__(256) void gemm_bt(
    const bf16* __restrict__ A, const bf16* __restrict__ BT, void* __restrict__ Cout,
    const float* __restrict__ bias, const float* __restrict__ rowadd,
    int M, int Nc, int K) {
  constexpr int PK = 56;
  __shared__ short As[128 * PK];
  __shared__ short Bs[128 * PK];
  const int tid = threadIdx.x;
  const int l = tid & 63, w = tid >> 6;
  const int wr = (w >> 1) * 64, wc = (w & 1) * 64;
  const int brow = blockIdx.y * 128, bcol = blockIdx.x * 128;
  const int lr = l & 15, lg = l >> 4, lk = (l >> 4) * 8;
  f32x4 acc[4][4] = {};
  for (int k0 = 0; k0 < K; k0 += 32) {
#pragma unroll
    for (int c0 = 0; c0 < 512; c0 += 256) {
      int c = c0 + tid;
      int row = c >> 2, kc = (c & 3) * 8;
      *reinterpret_cast<uint4*>(&As[row * PK + kc]) =
          *reinterpret_cast<const uint4*>(A + (size_t)(brow + row) * K + k0 + kc);
      *reinterpret_cast<uint4*>(&Bs[row * PK + kc]) =
          *reinterpret_cast<const uint4*>(BT + (size_t)(bcol + row) * K + k0 + kc);
    }
    __syncthreads();
    bf16x8s a[4], bfr[4];
#pragma unroll
    for (int m = 0; m < 4; m++)
      a[m] = *reinterpret_cast<const bf16x8s*>(&As[(wr + m * 16 + lr) * PK + lk]);
#pragma unroll
    for (int n = 0; n < 4; n++)
      bfr[n] = *reinterpret_cast<const bf16x8s*>(&Bs[(wc + n * 16 + lr) * PK + lk]);
#pragma unroll
    for (int m = 0; m < 4; m++)
#pragma unroll
      for (int n = 0; n < 4; n++)
        acc[m][n] = __builtin_amdgcn_mfma_f32_16x16x32_bf16(a[m], bfr[n], acc[m][n], 0, 0, 0);
    __syncthreads();
  }
#pragma unroll
  for (int m = 0; m < 4; m++) {
#pragma unroll
    for (int n = 0; n < 4; n++) {
      int col = bcol + wc + n * 16 + lr;
      float bv = bias[col];
#pragma unroll
      for (int r = 0; r < 4; r++) {
        int row = brow + wr + m * 16 + lg * 4 + r;
        float v = acc[m][n][r] + bv;
        if (HAS_ROWADD) v += rowadd[(size_t)(row & (NN - 1)) * Nc + col];
        if (OUT_BF16)
          reinterpret_cast<bf16*>(Cout)[(size_t)row * Nc + col] = __float2bfloat16(v);
        else
          reinterpret_cast<float*>(Cout)[(size_t)row * Nc + col] = v;
      }
    }
  }
}

// ---------------- flash attention with multiplicative mask ----------------
// grid (N/64, H, B), 256 thr. Wave w owns 16 q-rows. KV tile = 64.
__global__ __launch_bounds__(256) void attn_k(
    const bf16* __restrict__ Qb, const bf16* __restrict__ Kb, const bf16* __restrict__ Vb,
    const float* __restrict__ mask, bf16* __restrict__ Ob) {
  constexpr int PAD = 88;  // 176B rows: 16B-aligned, benign bank pattern
  __shared__ short Ks[64 * PAD];
  __shared__ short Vts[64 * PAD];
  __shared__ short Ps[4][16 * PAD];
  const int tid = threadIdx.x;
  const int l = tid & 63, w = tid >> 6;
  const int b = blockIdx.z, h = blockIdx.y, q0 = blockIdx.x * 64;
  const int lr = l & 15, lg = l >> 4, lk = (l >> 4) * 8;

  const size_t qoff = (size_t)(b * NN + q0 + w * 16 + lr) * DD + h * 64;
  bf16x8s qf0 = *reinterpret_cast<const bf16x8s*>(Qb + qoff + lk);
  bf16x8s qf1 = *reinterpret_cast<const bf16x8s*>(Qb + qoff + 32 + lk);

  f32x4 acc[4] = {};
  float mrun[4], lrun[4];
#pragma unroll
  for (int r = 0; r < 4; r++) { mrun[r] = -1e30f; lrun[r] = 0.f; }

  for (int jt = 0; jt < NN; jt += 64) {
    __syncthreads();  // protect Ks/Vts from previous iteration's readers
#pragma unroll
    for (int c0 = 0; c0 < 512; c0 += 256) {
      int c = c0 + tid;
      int j = c >> 3, cc = (c & 7) * 8;
      size_t goff = (size_t)(b * NN + jt + j) * DD + h * 64 + cc;
      *reinterpret_cast<uint4*>(&Ks[j * PAD + cc]) = *reinterpret_cast<const uint4*>(Kb + goff);
      uint4 vv = *reinterpret_cast<const uint4*>(Vb + goff);
      const short* vs = reinterpret_cast<const short*>(&vv);
#pragma unroll
      for (int e = 0; e < 8; e++) Vts[(cc + e) * PAD + j] = vs[e];  // V transposed: Vts[d][j]
    }
    __syncthreads();

    // S = Q K^T  (16 q-rows x 64 j)
    f32x4 s[4];
#pragma unroll
    for (int jj = 0; jj < 4; jj++) {
      bf16x8s k0 = *reinterpret_cast<const bf16x8s*>(&Ks[(jj * 16 + lr) * PAD + lk]);
      bf16x8s k1 = *reinterpret_cast<const bf16x8s*>(&Ks[(jj * 16 + lr) * PAD + 32 + lk]);
      f32x4 z = {0.f, 0.f, 0.f, 0.f};
      z = __builtin_amdgcn_mfma_f32_16x16x32_bf16(qf0, k0, z, 0, 0, 0);
      s[jj] = __builtin_amdgcn_mfma_f32_16x16x32_bf16(qf1, k1, z, 0, 0, 0);
    }

    // scale + multiplicative mask
    float pv[4][4];  // [jj][r]
#pragma unroll
    for (int jj = 0; jj < 4; jj++)
#pragma unroll
      for (int r = 0; r < 4; r++) {
        int grow = q0 + w * 16 + lg * 4 + r;
        int gcol = jt + jj * 16 + lr;
        pv[jj][r] = s[jj][r] * 0.125f * mask[(size_t)grow * NN + gcol];
      }

    // online softmax per row
    short* Pw = &Ps[w][0];
#pragma unroll
    for (int r = 0; r < 4; r++) {
      float mx = fmaxf(fmaxf(pv[0][r], pv[1][r]), fmaxf(pv[2][r], pv[3][r]));
#pragma unroll
      for (int off = 8; off >= 1; off >>= 1) mx = fmaxf(mx, __shfl_xor(mx, off, 64));
      float mnew = fmaxf(mrun[r], mx);
      float scale = __expf(mrun[r] - mnew);
      float rs = 0.f;
#pragma unroll
      for (int jj = 0; jj < 4; jj++) {
        float p = __expf(pv[jj][r] - mnew);
        pv[jj][r] = p;
        rs += p;
      }
#pragma unroll
      for (int off = 8; off >= 1; off >>= 1) rs += __shfl_xor(rs, off, 64);
      lrun[r] = lrun[r] * scale + rs;
      mrun[r] = mnew;
#pragma unroll
      for (int s4 = 0; s4 < 4; s4++) acc[s4][r] *= scale;
    }
    // write P (bf16) to LDS in A-fragment-friendly layout
#pragma unroll
    for (int jj = 0; jj < 4; jj++)
#pragma unroll
      for (int r = 0; r < 4; r++) {
        bf16 pb = __float2bfloat16(pv[jj][r]);
        Pw[(lg * 4 + r) * PAD + jj * 16 + lr] = *reinterpret_cast<short*>(&pb);
      }
    __syncthreads();

    // O += P V
    bf16x8s pa0 = *reinterpret_cast<const bf16x8s*>(&Pw[lr * PAD + lk]);
    bf16x8s pa1 = *reinterpret_cast<const bf16x8s*>(&Pw[lr * PAD + 32 + lk]);
#pragma unroll
    for (int s4 = 0; s4 < 4; s4++) {
      bf16x8s v0 = *reinterpret_cast<const bf16x8s*>(&Vts[(s4 * 16 + lr) * PAD + lk]);
      bf16x8s v1 = *reinterpret_cast<const bf16x8s*>(&Vts[(s4 * 16 + lr) * PAD + 32 + lk]);
      acc[s4] = __builtin_amdgcn_mfma_f32_16x16x32_bf16(pa0, v0, acc[s4], 0, 0, 0);
      acc[s4] = __builtin_amdgcn_mfma_f32_16x16x32_bf16(pa1, v1, acc[s4], 0, 0, 0);
    }
  }

  // epilogue: normalize and store attention output (bf16)
#pragma unroll
  for (int s4 = 0; s4 < 4; s4++)
#pragma unroll
    for (int r = 0; r < 4; r++) {
      size_t row = (size_t)(b * NN + q0 + w * 16 + lg * 4 + r);
      float v = acc[s4][r] / lrun[r];
      Ob[row * DD + h * 64 + s4 * 16 + lr] = __float2bfloat16(v);
    }
}

// ---------------- orchestration ----------------
extern "C" void kernel_launch(void* const* d_in, const int* in_sizes, int n_in,
                              void* d_out, int out_size, void* d_ws, size_t ws_size,
                              hipStream_t stream) {
  (void)in_sizes; (void)n_in; (void)out_size; (void)ws_size;
  const float* x    = (const float*)d_in[0];
  const float* cg   = (const float*)d_in[1];
  const float* mask = (const float*)d_in[2];
  const float* Wq   = (const float*)d_in[3];
  const float* bq   = (const float*)d_in[4];
  const float* Wk   = (const float*)d_in[5];
  const float* bk   = (const float*)d_in[6];
  const float* Wc   = (const float*)d_in[7];
  const float* bc   = (const float*)d_in[8];
  const float* We   = (const float*)d_in[9];
  const float* be   = (const float*)d_in[10];
  const float* Wv   = (const float*)d_in[11];
  const float* bv   = (const float*)d_in[12];
  const float* Wo   = (const float*)d_in[13];
  const float* bo   = (const float*)d_in[14];

  auto MB = [](size_t m) { return m << 20; };
  char* ws = (char*)d_ws;
  bf16* xb   = (bf16*)(ws + MB(0));    // 16 MB
  bf16* WqT  = (bf16*)(ws + MB(16));   // 2 MB each
  bf16* WkT  = (bf16*)(ws + MB(18));
  bf16* WvT  = (bf16*)(ws + MB(20));
  bf16* WoT  = (bf16*)(ws + MB(22));
  float* cq  = (float*)(ws + MB(24));  // 8 MB f32
  float* ck  = (float*)(ws + MB(32));  // 8 MB f32
  bf16* Qb   = (bf16*)(ws + MB(40));   // 16 MB
  bf16* Kb   = (bf16*)(ws + MB(56));   // 16 MB
  bf16* Vb   = (bf16*)(ws + MB(72));   // 16 MB
  bf16* Ob   = (bf16*)(ws + MB(88));   // 16 MB -> peak 104 MB
  // overlays, dead after G1/G2 (before Qb/Kb are written):
  bf16* WcT  = (bf16*)(ws + MB(40));   // 4 MB
  bf16* WeT  = (bf16*)(ws + MB(44));   // 4 MB
  bf16* cgb  = (bf16*)(ws + MB(48));   // 8 MB
  bf16* cgT  = (bf16*)(ws + MB(56));   // 8 MB

  cast_f32_bf16<<<dim3(BB * NN * DD / 4 / 256), 256, 0, stream>>>(x, xb, BB * NN * DD);
  cast_f32_bf16<<<dim3(NN * NN / 4 / 256), 256, 0, stream>>>(cg, cgb, NN * NN);
  dim3 tb(32, 8);
  transpose_cast<<<dim3(DD / 32, DD / 32), tb, 0, stream>>>(Wq, WqT, DD, DD);
  transpose_cast<<<dim3(DD / 32, DD / 32), tb, 0, stream>>>(Wk, WkT, DD, DD);
  transpose_cast<<<dim3(DD / 32, DD / 32), tb, 0, stream>>>(Wv, WvT, DD, DD);
  transpose_cast<<<dim3(DD / 32, DD / 32), tb, 0, stream>>>(Wo, WoT, DD, DD);
  transpose_cast<<<dim3(DD / 32, NN / 32), tb, 0, stream>>>(Wc, WcT, NN, DD);
  transpose_cast<<<dim3(DD / 32, NN / 32), tb, 0, stream>>>(We, WeT, NN, DD);
  transpose_cast<<<dim3(NN / 32, NN / 32), tb, 0, stream>>>(cg, cgT, NN, NN);

  // cq = cg@Wc + bc ; ck = cg^T@We + be   (f32 out)
  gemm_bt<0, 0><<<dim3(DD / 128, NN / 128), 256, 0, stream>>>(cgb, WcT, cq, bc, nullptr, NN, DD, NN);
  gemm_bt<0, 0><<<dim3(DD / 128, NN / 128), 256, 0, stream>>>(cgT, WeT, ck, be, nullptr, NN, DD, NN);
  // Q = x@Wq + bq + cq[row] ; K = x@Wk + bk + ck[row] ; V = x@Wv + bv   (bf16 out)
  gemm_bt<1, 1><<<dim3(DD / 128, BB * NN / 128), 256, 0, stream>>>(xb, WqT, Qb, bq, cq, BB * NN, DD, DD);
  gemm_bt<1, 1><<<dim3(DD / 128, BB * NN / 128), 256, 0, stream>>>(xb, WkT, Kb, bk, ck, BB * NN, DD, DD);
  gemm_bt<1, 0><<<dim3(DD / 128, BB * NN / 128), 256, 0, stream>>>(xb, WvT, Vb, bv, nullptr, BB * NN, DD, DD);

  attn_k<<<dim3(NN / 64, HH, BB), 256, 0, stream>>>(Qb, Kb, Vb, mask, Ob);

  // out = attn@Wo + bo  (f32 out)
  gemm_bt<0, 0><<<dim3(DD / 128, BB * NN / 128), 256, 0, stream>>>(Ob, WoT, (float*)d_out, bo, nullptr, BB * NN, DD, DD);
}

// Round 2
// 535.532 us; speedup vs baseline: 1.1017x; 1.1017x over previous
//
#include <hip/hip_runtime.h>
#include <hip/hip_bf16.h>

#define BB 4
#define NN 2048
#define DD 1024
#define HH 16

using bf16 = __hip_bfloat16;
typedef __attribute__((ext_vector_type(8))) short bf16x8s;
typedef __attribute__((ext_vector_type(4))) float f32x4;

#define GLOAD_LDS16(gp, lp)                                                   \
  __builtin_amdgcn_global_load_lds(                                           \
      (const __attribute__((address_space(1))) void*)(gp),                    \
      (__attribute__((address_space(3))) void*)(lp), 16, 0, 0)

// ---------------- cast f32 -> bf16 (vectorized x4) ----------------
__global__ void cast_f32_bf16(const float* __restrict__ in, bf16* __restrict__ out, int n) {
  int i = (blockIdx.x * blockDim.x + threadIdx.x) * 4;
  if (i >= n) return;
  float4 v = *reinterpret_cast<const float4*>(in + i);
  ushort4 o;
  bf16 t0 = __float2bfloat16(v.x); o.x = *reinterpret_cast<unsigned short*>(&t0);
  bf16 t1 = __float2bfloat16(v.y); o.y = *reinterpret_cast<unsigned short*>(&t1);
  bf16 t2 = __float2bfloat16(v.z); o.z = *reinterpret_cast<unsigned short*>(&t2);
  bf16 t3 = __float2bfloat16(v.w); o.w = *reinterpret_cast<unsigned short*>(&t3);
  *reinterpret_cast<ushort4*>(out + i) = o;
}

// ---------------- transpose + cast: in[R,C] f32 -> out[C,R] bf16 ----------------
__global__ void transpose_cast(const float* __restrict__ in, bf16* __restrict__ out, int R, int C) {
  __shared__ float t[32][33];
  int c0 = blockIdx.x * 32, r0 = blockIdx.y * 32;
  int tx = threadIdx.x, ty = threadIdx.y;  // block (32,8)
#pragma unroll
  for (int i = 0; i < 4; i++)
    t[ty + i * 8][tx] = in[(size_t)(r0 + ty + i * 8) * C + c0 + tx];
  __syncthreads();
#pragma unroll
  for (int i = 0; i < 4; i++)
    out[(size_t)(c0 + ty + i * 8) * R + r0 + tx] = __float2bfloat16(t[tx][ty + i * 8]);
}

// ---------------- bf16->bf16 transpose of V into per-head layout ----------------
// Vb [B*N][D] -> Vt [B*H][64][N]  (Vt[bh][d][n] = Vb[b*N+n][h*64+d])
__global__ void transpose_v(const bf16* __restrict__ Vb, bf16* __restrict__ Vt) {
  __shared__ short t[32][33];
  int bh = blockIdx.z; int b = bh >> 4, h = bh & 15;
  int n0 = blockIdx.x * 32, d0 = blockIdx.y * 32;
  int tx = threadIdx.x, ty = threadIdx.y;  // block (32,8)
#pragma unroll
  for (int i = 0; i < 4; i++)
    t[ty + i * 8][tx] = reinterpret_cast<const short*>(Vb)[
        (size_t)(b * NN + n0 + ty + i * 8) * DD + h * 64 + d0 + tx];
  __syncthreads();
#pragma unroll
  for (int i = 0; i < 4; i++)
    reinterpret_cast<short*>(Vt)[(size_t)(bh * 64 + d0 + ty + i * 8) * NN + n0 + tx] =
        t[tx][ty + i * 8];
}

// ---------------- bf16 MFMA GEMM: C[M,Nc] = scale*(A[M,K] * BT[Nc,K]^T + bias (+rowadd)) ----
// 128x128 tile, BK=32, 4 waves (2x2). Staging via global_load_lds width=16, linear
// [128][32] LDS (row=64B). Fragment read (row)*32+lg*8: bank-floor (verified: 8 acc/bank).
template <int OUT_BF16, int HAS_ROWADD>
__global__ __launch_bounds__(256) void gemm_bt(
    const bf16* __restrict__ A, const bf16* __restrict__ BT, void* __restrict__ Cout,
    const float* __restrict__ bias, const float* __restrict__ rowadd,
    int M, int Nc, int K, float scale) {
  __shared__ short As[128 * 32];
  __shared__ short Bs[128 * 32];
  const int tid = threadIdx.x;
  const int l = tid & 63, w = tid >> 6;
  const int wr = (w >> 1) * 64, wc = (w & 1) * 64;
  const int brow = blockIdx.y * 128, bcol = blockIdx.x * 128;
  const int lr = l & 15, lg = l >> 4, lk = lg * 8;
  f32x4 acc[4][4] = {};
  for (int k0 = 0; k0 < K; k0 += 32) {
#pragma unroll
    for (int i = 0; i < 2; i++) {
      int c = i * 256 + tid;
      int row = c >> 2, cc = (c & 3) * 8;
      short* lbase = (short*)As + (size_t)(i * 256 + w * 64) * 8;  // wave-uniform
      GLOAD_LDS16(A + (size_t)(brow + row) * K + k0 + cc, lbase);
      short* lbaseB = (short*)Bs + (size_t)(i * 256 + w * 64) * 8;
      GLOAD_LDS16(BT + (size_t)(bcol + row) * K + k0 + cc, lbaseB);
    }
    __syncthreads();
    bf16x8s a[4], bfr[4];
#pragma unroll
    for (int m = 0; m < 4; m++)
      a[m] = *reinterpret_cast<const bf16x8s*>(&As[(wr + m * 16 + lr) * 32 + lk]);
#pragma unroll
    for (int n = 0; n < 4; n++)
      bfr[n] = *reinterpret_cast<const bf16x8s*>(&Bs[(wc + n * 16 + lr) * 32 + lk]);
#pragma unroll
    for (int m = 0; m < 4; m++)
#pragma unroll
      for (int n = 0; n < 4; n++)
        acc[m][n] = __builtin_amdgcn_mfma_f32_16x16x32_bf16(a[m], bfr[n], acc[m][n], 0, 0, 0);
    __syncthreads();
  }
#pragma unroll
  for (int m = 0; m < 4; m++) {
#pragma unroll
    for (int n = 0; n < 4; n++) {
      int col = bcol + wc + n * 16 + lr;
      float bv = bias[col];
#pragma unroll
      for (int r = 0; r < 4; r++) {
        int row = brow + wr + m * 16 + lg * 4 + r;
        float v = acc[m][n][r] + bv;
        if (HAS_ROWADD) v += rowadd[(size_t)(row & (NN - 1)) * Nc + col];
        v *= scale;
        if (OUT_BF16)
          reinterpret_cast<bf16*>(Cout)[(size_t)row * Nc + col] = __float2bfloat16(v);
        else
          reinterpret_cast<float*>(Cout)[(size_t)row * Nc + col] = v;
      }
    }
  }
}

// ---------------- flash attention with multiplicative mask ----------------
// grid (N/64, H, B), 256 thr. Wave w owns 16 q-rows. KV tile = 64.
// K and Vt staged via global_load_lds (linear [64][64], fragment reads at bank-floor).
// Q pre-scaled by 1/sqrt(DK) in its GEMM epilogue.
__global__ __launch_bounds__(256) void attn_k(
    const bf16* __restrict__ Qb, const bf16* __restrict__ Kb, const bf16* __restrict__ Vt,
    const float* __restrict__ mask, bf16* __restrict__ Ob) {
  constexpr int PPAD = 72;  // P rows 144B: 2-way-max (free) on write & read
  __shared__ short Ks[64 * 64];
  __shared__ short Vts[64 * 64];
  __shared__ short Ps[4][16 * PPAD];
  const int tid = threadIdx.x;
  const int l = tid & 63, w = tid >> 6;
  const int b = blockIdx.z, h = blockIdx.y, q0 = blockIdx.x * 64;
  const int lr = l & 15, lg = l >> 4, lk = lg * 8;

  const size_t qoff = (size_t)(b * NN + q0 + w * 16 + lr) * DD + h * 64;
  bf16x8s qf0 = *reinterpret_cast<const bf16x8s*>(Qb + qoff + lk);
  bf16x8s qf1 = *reinterpret_cast<const bf16x8s*>(Qb + qoff + 32 + lk);

  f32x4 acc[4] = {};
  float mrun[4], lrun[4];
#pragma unroll
  for (int r = 0; r < 4; r++) { mrun[r] = -1e30f; lrun[r] = 0.f; }

  const size_t kbase = (size_t)b * NN * DD + h * 64;
  const size_t vbase = (size_t)(b * HH + h) * 64 * NN;

  for (int jt = 0; jt < NN; jt += 64) {
    __syncthreads();  // prior tile's readers done before overwrite
#pragma unroll
    for (int i = 0; i < 2; i++) {
      int c = i * 256 + tid;
      int j = c >> 3, cc = (c & 7) * 8;
      short* lbK = (short*)Ks + (size_t)(i * 256 + w * 64) * 8;  // wave-uniform
      GLOAD_LDS16(Kb + kbase + (size_t)(jt + j) * DD + cc, lbK);
      short* lbV = (short*)Vts + (size_t)(i * 256 + w * 64) * 8;
      GLOAD_LDS16(Vt + vbase + (size_t)j * NN + jt + cc, lbV);
    }
    __syncthreads();

    // S = Q K^T  (16 q-rows x 64 j)
    f32x4 s[4];
#pragma unroll
    for (int jj = 0; jj < 4; jj++) {
      bf16x8s k0 = *reinterpret_cast<const bf16x8s*>(&Ks[(jj * 16 + lr) * 64 + lk]);
      bf16x8s k1 = *reinterpret_cast<const bf16x8s*>(&Ks[(jj * 16 + lr) * 64 + 32 + lk]);
      f32x4 z = {0.f, 0.f, 0.f, 0.f};
      z = __builtin_amdgcn_mfma_f32_16x16x32_bf16(qf0, k0, z, 0, 0, 0);
      s[jj] = __builtin_amdgcn_mfma_f32_16x16x32_bf16(qf1, k1, z, 0, 0, 0);
    }

    // multiplicative mask (scale already folded into Q)
    float pv[4][4];  // [jj][r]
#pragma unroll
    for (int jj = 0; jj < 4; jj++)
#pragma unroll
      for (int r = 0; r < 4; r++) {
        int grow = q0 + w * 16 + lg * 4 + r;
        int gcol = jt + jj * 16 + lr;
        pv[jj][r] = s[jj][r] * mask[(size_t)grow * NN + gcol];
      }

    // online softmax per row (16-lane groups along lr)
    short* Pw = &Ps[w][0];
#pragma unroll
    for (int r = 0; r < 4; r++) {
      float mx = fmaxf(fmaxf(pv[0][r], pv[1][r]), fmaxf(pv[2][r], pv[3][r]));
#pragma unroll
      for (int off = 8; off >= 1; off >>= 1) mx = fmaxf(mx, __shfl_xor(mx, off, 64));
      float mnew = fmaxf(mrun[r], mx);
      float scale = __expf(mrun[r] - mnew);
      float rs = 0.f;
#pragma unroll
      for (int jj = 0; jj < 4; jj++) {
        float p = __expf(pv[jj][r] - mnew);
        pv[jj][r] = p;
        rs += p;
      }
#pragma unroll
      for (int off = 8; off >= 1; off >>= 1) rs += __shfl_xor(rs, off, 64);
      lrun[r] = lrun[r] * scale + rs;
      mrun[r] = mnew;
#pragma unroll
      for (int s4 = 0; s4 < 4; s4++) acc[s4][r] *= scale;
    }
    // write P (bf16) to LDS in A-fragment layout
#pragma unroll
    for (int jj = 0; jj < 4; jj++)
#pragma unroll
      for (int r = 0; r < 4; r++) {
        bf16 pb = __float2bfloat16(pv[jj][r]);
        Pw[(lg * 4 + r) * PPAD + jj * 16 + lr] = *reinterpret_cast<short*>(&pb);
      }
    __syncthreads();

    // O += P V
    bf16x8s pa0 = *reinterpret_cast<const bf16x8s*>(&Pw[lr * PPAD + lk]);
    bf16x8s pa1 = *reinterpret_cast<const bf16x8s*>(&Pw[lr * PPAD + 32 + lk]);
#pragma unroll
    for (int s4 = 0; s4 < 4; s4++) {
      bf16x8s v0 = *reinterpret_cast<const bf16x8s*>(&Vts[(s4 * 16 + lr) * 64 + lk]);
      bf16x8s v1 = *reinterpret_cast<const bf16x8s*>(&Vts[(s4 * 16 + lr) * 64 + 32 + lk]);
      acc[s4] = __builtin_amdgcn_mfma_f32_16x16x32_bf16(pa0, v0, acc[s4], 0, 0, 0);
      acc[s4] = __builtin_amdgcn_mfma_f32_16x16x32_bf16(pa1, v1, acc[s4], 0, 0, 0);
    }
  }

  // epilogue: normalize and store attention output (bf16)
#pragma unroll
  for (int s4 = 0; s4 < 4; s4++)
#pragma unroll
    for (int r = 0; r < 4; r++) {
      size_t row = (size_t)(b * NN + q0 + w * 16 + lg * 4 + r);
      float v = acc[s4][r] / lrun[r];
      Ob[row * DD + h * 64 + s4 * 16 + lr] = __float2bfloat16(v);
    }
}

// ---------------- orchestration ----------------
extern "C" void kernel_launch(void* const* d_in, const int* in_sizes, int n_in,
                              void* d_out, int out_size, void* d_ws, size_t ws_size,
                              hipStream_t stream) {
  (void)in_sizes; (void)n_in; (void)out_size; (void)ws_size;
  const float* x    = (const float*)d_in[0];
  const float* cg   = (const float*)d_in[1];
  const float* mask = (const float*)d_in[2];
  const float* Wq   = (const float*)d_in[3];
  const float* bq   = (const float*)d_in[4];
  const float* Wk   = (const float*)d_in[5];
  const float* bk   = (const float*)d_in[6];
  const float* Wc   = (const float*)d_in[7];
  const float* bc   = (const float*)d_in[8];
  const float* We   = (const float*)d_in[9];
  const float* be   = (const float*)d_in[10];
  const float* Wv   = (const float*)d_in[11];
  const float* bv   = (const float*)d_in[12];
  const float* Wo   = (const float*)d_in[13];
  const float* bo   = (const float*)d_in[14];

  auto MB = [](size_t m) { return m << 20; };
  char* ws = (char*)d_ws;
  bf16* xb   = (bf16*)(ws + MB(0));    // 16 MB
  bf16* WqT  = (bf16*)(ws + MB(16));   // 2 MB each
  bf16* WkT  = (bf16*)(ws + MB(18));
  bf16* WvT  = (bf16*)(ws + MB(20));
  bf16* WoT  = (bf16*)(ws + MB(22));
  float* cq  = (float*)(ws + MB(24));  // 8 MB f32
  float* ck  = (float*)(ws + MB(32));  // 8 MB f32
  bf16* Qb   = (bf16*)(ws + MB(40));   // 16 MB
  bf16* Kb   = (bf16*)(ws + MB(56));   // 16 MB
  bf16* Vb   = (bf16*)(ws + MB(72));   // 16 MB (dead after transpose_v)
  bf16* Vt   = (bf16*)(ws + MB(88));   // 16 MB -> peak 104 MB
  bf16* Ob   = (bf16*)(ws + MB(72));   // overlays Vb (dead)
  // overlays, dead after cq/ck GEMMs (before Qb/Kb are written):
  bf16* WcT  = (bf16*)(ws + MB(40));   // 4 MB
  bf16* WeT  = (bf16*)(ws + MB(44));   // 4 MB
  bf16* cgb  = (bf16*)(ws + MB(48));   // 8 MB
  bf16* cgT  = (bf16*)(ws + MB(56));   // 8 MB

  cast_f32_bf16<<<dim3(BB * NN * DD / 4 / 256), 256, 0, stream>>>(x, xb, BB * NN * DD);
  cast_f32_bf16<<<dim3(NN * NN / 4 / 256), 256, 0, stream>>>(cg, cgb, NN * NN);
  dim3 tb(32, 8);
  transpose_cast<<<dim3(DD / 32, DD / 32), tb, 0, stream>>>(Wq, WqT, DD, DD);
  transpose_cast<<<dim3(DD / 32, DD / 32), tb, 0, stream>>>(Wk, WkT, DD, DD);
  transpose_cast<<<dim3(DD / 32, DD / 32), tb, 0, stream>>>(Wv, WvT, DD, DD);
  transpose_cast<<<dim3(DD / 32, DD / 32), tb, 0, stream>>>(Wo, WoT, DD, DD);
  transpose_cast<<<dim3(DD / 32, NN / 32), tb, 0, stream>>>(Wc, WcT, NN, DD);
  transpose_cast<<<dim3(DD / 32, NN / 32), tb, 0, stream>>>(We, WeT, NN, DD);
  transpose_cast<<<dim3(NN / 32, NN / 32), tb, 0, stream>>>(cg, cgT, NN, NN);

  // cq = cg@Wc + bc ; ck = cg^T@We + be   (f32 out)
  gemm_bt<0, 0><<<dim3(DD / 128, NN / 128), 256, 0, stream>>>(cgb, WcT, cq, bc, nullptr, NN, DD, NN, 1.0f);
  gemm_bt<0, 0><<<dim3(DD / 128, NN / 128), 256, 0, stream>>>(cgT, WeT, ck, be, nullptr, NN, DD, NN, 1.0f);
  // Q = 0.125*(x@Wq + bq + cq[row]) ; K = x@Wk + bk + ck[row] ; V = x@Wv + bv   (bf16 out)
  gemm_bt<1, 1><<<dim3(DD / 128, BB * NN / 128), 256, 0, stream>>>(xb, WqT, Qb, bq, cq, BB * NN, DD, DD, 0.125f);
  gemm_bt<1, 1><<<dim3(DD / 128, BB * NN / 128), 256, 0, stream>>>(xb, WkT, Kb, bk, ck, BB * NN, DD, DD, 1.0f);
  gemm_bt<1, 0><<<dim3(DD / 128, BB * NN / 128), 256, 0, stream>>>(xb, WvT, Vb, bv, nullptr, BB * NN, DD, DD, 1.0f);

  transpose_v<<<dim3(NN / 32, 2, BB * HH), tb, 0, stream>>>(Vb, Vt);

  attn_k<<<dim3(NN / 64, HH, BB), 256, 0, stream>>>(Qb, Kb, Vt, mask, Ob);

  // out = attn@Wo + bo  (f32 out)
  gemm_bt<0, 0><<<dim3(DD / 128, BB * NN / 128), 256, 0, stream>>>(Ob, WoT, (float*)d_out, bo, nullptr, BB * NN, DD, DD, 1.0f);
}

// Round 3
// 439.381 us; speedup vs baseline: 1.3428x; 1.2188x over previous
//
#include <hip/hip_runtime.h>
#include <hip/hip_bf16.h>

#define BB 4
#define NN 2048
#define DD 1024
#define HH 16

using bf16 = __hip_bfloat16;
typedef __attribute__((ext_vector_type(8))) short bf16x8s;
typedef __attribute__((ext_vector_type(4))) float f32x4;

#define GLOAD_LDS16(gp, lp)                                                   \
  __builtin_amdgcn_global_load_lds(                                           \
      (const __attribute__((address_space(1))) void*)(gp),                    \
      (__attribute__((address_space(3))) void*)(lp), 16, 0, 0)

// ---------------- cast f32 -> bf16 (vectorized x4) ----------------
__global__ void cast_f32_bf16(const float* __restrict__ in, bf16* __restrict__ out, int n) {
  int i = (blockIdx.x * blockDim.x + threadIdx.x) * 4;
  if (i >= n) return;
  float4 v = *reinterpret_cast<const float4*>(in + i);
  ushort4 o;
  bf16 t0 = __float2bfloat16(v.x); o.x = *reinterpret_cast<unsigned short*>(&t0);
  bf16 t1 = __float2bfloat16(v.y); o.y = *reinterpret_cast<unsigned short*>(&t1);
  bf16 t2 = __float2bfloat16(v.z); o.z = *reinterpret_cast<unsigned short*>(&t2);
  bf16 t3 = __float2bfloat16(v.w); o.w = *reinterpret_cast<unsigned short*>(&t3);
  *reinterpret_cast<ushort4*>(out + i) = o;
}

// ---------------- transpose + cast: in[R,C] f32 -> out[C,R] bf16 ----------------
__global__ void transpose_cast(const float* __restrict__ in, bf16* __restrict__ out, int R, int C) {
  __shared__ float t[32][33];
  int c0 = blockIdx.x * 32, r0 = blockIdx.y * 32;
  int tx = threadIdx.x, ty = threadIdx.y;  // block (32,8)
#pragma unroll
  for (int i = 0; i < 4; i++)
    t[ty + i * 8][tx] = in[(size_t)(r0 + ty + i * 8) * C + c0 + tx];
  __syncthreads();
#pragma unroll
  for (int i = 0; i < 4; i++)
    out[(size_t)(c0 + ty + i * 8) * R + r0 + tx] = __float2bfloat16(t[tx][ty + i * 8]);
}

// ---------------- bf16->bf16 transpose of V into per-head layout ----------------
// Vb [B*N][D] -> Vt [B*H][64][N]  (Vt[bh][d][n] = Vb[b*N+n][h*64+d])
__global__ void transpose_v(const bf16* __restrict__ Vb, bf16* __restrict__ Vt) {
  __shared__ short t[32][33];
  int bh = blockIdx.z; int b = bh >> 4, h = bh & 15;
  int n0 = blockIdx.x * 32, d0 = blockIdx.y * 32;
  int tx = threadIdx.x, ty = threadIdx.y;  // block (32,8)
#pragma unroll
  for (int i = 0; i < 4; i++)
    t[ty + i * 8][tx] = reinterpret_cast<const short*>(Vb)[
        (size_t)(b * NN + n0 + ty + i * 8) * DD + h * 64 + d0 + tx];
  __syncthreads();
#pragma unroll
  for (int i = 0; i < 4; i++)
    reinterpret_cast<short*>(Vt)[(size_t)(bh * 64 + d0 + ty + i * 8) * NN + n0 + tx] =
        t[tx][ty + i * 8];
}

// ---------------- bf16 MFMA GEMM: C[M,Nc] = scale*(A[M,K] * BT[Nc,K]^T + bias (+rowadd)) ----
// 128x128 tile, BK=64, 4 waves (2x2). Staging via global_load_lds width=16 into linear
// [128][64] LDS; XOR chunk-swizzle (chunk ^= row&7) applied on the GLOBAL source and on
// the ds_read address (rule #21: both sides). Fragment reads: 2 lanes/bank-cluster = floor.
template <int OUT_BF16, int HAS_ROWADD>
__global__ __launch_bounds__(256) void gemm_bt(
    const bf16* __restrict__ A, const bf16* __restrict__ BT, void* __restrict__ Cout,
    const float* __restrict__ bias, const float* __restrict__ rowadd,
    int M, int Nc, int K, float scale) {
  __shared__ short As[128 * 64];
  __shared__ short Bs[128 * 64];
  const int tid = threadIdx.x;
  const int l = tid & 63, w = tid >> 6;
  const int wr = (w >> 1) * 64, wc = (w & 1) * 64;
  const int brow = blockIdx.y * 128, bcol = blockIdx.x * 128;
  const int lr = l & 15, lg = l >> 4;
  const int swz = lr & 7;
  f32x4 acc[4][4] = {};
  for (int k0 = 0; k0 < K; k0 += 64) {
#pragma unroll
    for (int i = 0; i < 4; i++) {
      int c = i * 256 + tid;          // chunk index 0..1023 (16B chunks)
      int row = c >> 3, gch = (c & 7) ^ (row & 7);
      short* lA = (short*)As + (size_t)(i * 256 + w * 64) * 8;  // wave-uniform dest
      GLOAD_LDS16(A + (size_t)(brow + row) * K + k0 + gch * 8, lA);
      short* lB = (short*)Bs + (size_t)(i * 256 + w * 64) * 8;
      GLOAD_LDS16(BT + (size_t)(bcol + row) * K + k0 + gch * 8, lB);
    }
    __syncthreads();
#pragma unroll
    for (int t = 0; t < 2; t++) {
      bf16x8s a[4], bfr[4];
#pragma unroll
      for (int m = 0; m < 4; m++)
        a[m] = *reinterpret_cast<const bf16x8s*>(
            &As[(wr + m * 16 + lr) * 64 + ((t * 4 + lg) ^ swz) * 8]);
#pragma unroll
      for (int n = 0; n < 4; n++)
        bfr[n] = *reinterpret_cast<const bf16x8s*>(
            &Bs[(wc + n * 16 + lr) * 64 + ((t * 4 + lg) ^ swz) * 8]);
#pragma unroll
      for (int m = 0; m < 4; m++)
#pragma unroll
        for (int n = 0; n < 4; n++)
          acc[m][n] = __builtin_amdgcn_mfma_f32_16x16x32_bf16(a[m], bfr[n], acc[m][n], 0, 0, 0);
    }
    __syncthreads();
  }
#pragma unroll
  for (int m = 0; m < 4; m++) {
#pragma unroll
    for (int n = 0; n < 4; n++) {
      int col = bcol + wc + n * 16 + lr;
      float bv = bias[col];
#pragma unroll
      for (int r = 0; r < 4; r++) {
        int row = brow + wr + m * 16 + (l >> 4) * 4 + r;
        float v = acc[m][n][r] + bv;
        if (HAS_ROWADD) v += rowadd[(size_t)(row & (NN - 1)) * Nc + col];
        v *= scale;
        if (OUT_BF16)
          reinterpret_cast<bf16*>(Cout)[(size_t)row * Nc + col] = __float2bfloat16(v);
        else
          reinterpret_cast<float*>(Cout)[(size_t)row * Nc + col] = v;
      }
    }
  }
}

// ---------------- flash attention with multiplicative mask ----------------
// grid (N/64, H, B), 256 thr. Wave w owns 16 q-rows. KV tile = 64.
// K and Vt staged via global_load_lds into linear [64][64] LDS with XOR chunk-swizzle
// (source-permuted + swizzled ds_read). Q pre-scaled by 1/sqrt(DK) in its GEMM.
__global__ __launch_bounds__(256) void attn_k(
    const bf16* __restrict__ Qb, const bf16* __restrict__ Kb, const bf16* __restrict__ Vt,
    const float* __restrict__ mask, bf16* __restrict__ Ob) {
  constexpr int PPAD = 72;  // P reads at b128 floor; writes ~4-way scalar (minor)
  __shared__ short Ks[64 * 64];
  __shared__ short Vts[64 * 64];
  __shared__ short Ps[4][16 * PPAD];
  const int tid = threadIdx.x;
  const int l = tid & 63, w = tid >> 6;
  const int b = blockIdx.z, h = blockIdx.y, q0 = blockIdx.x * 64;
  const int lr = l & 15, lg = l >> 4, lk = lg * 8;
  const int swz = lr & 7;

  const size_t qoff = (size_t)(b * NN + q0 + w * 16 + lr) * DD + h * 64;
  bf16x8s qf0 = *reinterpret_cast<const bf16x8s*>(Qb + qoff + lk);
  bf16x8s qf1 = *reinterpret_cast<const bf16x8s*>(Qb + qoff + 32 + lk);

  f32x4 acc[4] = {};
  float mrun[4], lrun[4];
#pragma unroll
  for (int r = 0; r < 4; r++) { mrun[r] = -1e30f; lrun[r] = 0.f; }

  const size_t kbase = (size_t)b * NN * DD + h * 64;
  const size_t vbase = (size_t)(b * HH + h) * 64 * NN;

  for (int jt = 0; jt < NN; jt += 64) {
    __syncthreads();  // prior tile's readers done before overwrite
#pragma unroll
    for (int i = 0; i < 2; i++) {
      int c = i * 256 + tid;          // chunk 0..511
      int row = c >> 3, gch = (c & 7) ^ (row & 7);
      short* lbK = (short*)Ks + (size_t)(i * 256 + w * 64) * 8;  // wave-uniform dest
      GLOAD_LDS16(Kb + kbase + (size_t)(jt + row) * DD + gch * 8, lbK);
      short* lbV = (short*)Vts + (size_t)(i * 256 + w * 64) * 8;
      GLOAD_LDS16(Vt + vbase + (size_t)row * NN + jt + gch * 8, lbV);
    }
    __syncthreads();

    // S = Q K^T  (16 q-rows x 64 j)
    f32x4 s[4];
#pragma unroll
    for (int jj = 0; jj < 4; jj++) {
      bf16x8s k0 = *reinterpret_cast<const bf16x8s*>(
          &Ks[(jj * 16 + lr) * 64 + ((0 + lg) ^ swz) * 8]);
      bf16x8s k1 = *reinterpret_cast<const bf16x8s*>(
          &Ks[(jj * 16 + lr) * 64 + ((4 + lg) ^ swz) * 8]);
      f32x4 z = {0.f, 0.f, 0.f, 0.f};
      z = __builtin_amdgcn_mfma_f32_16x16x32_bf16(qf0, k0, z, 0, 0, 0);
      s[jj] = __builtin_amdgcn_mfma_f32_16x16x32_bf16(qf1, k1, z, 0, 0, 0);
    }

    // multiplicative mask (1/sqrt(dk) folded into Q)
    float pv[4][4];  // [jj][r]
#pragma unroll
    for (int jj = 0; jj < 4; jj++)
#pragma unroll
      for (int r = 0; r < 4; r++) {
        int grow = q0 + w * 16 + lg * 4 + r;
        int gcol = jt + jj * 16 + lr;
        pv[jj][r] = s[jj][r] * mask[(size_t)grow * NN + gcol];
      }

    // online softmax per row (16-lane groups along lr)
    short* Pw = &Ps[w][0];
#pragma unroll
    for (int r = 0; r < 4; r++) {
      float mx = fmaxf(fmaxf(pv[0][r], pv[1][r]), fmaxf(pv[2][r], pv[3][r]));
#pragma unroll
      for (int off = 8; off >= 1; off >>= 1) mx = fmaxf(mx, __shfl_xor(mx, off, 64));
      float mnew = fmaxf(mrun[r], mx);
      float scale = __expf(mrun[r] - mnew);
      float rs = 0.f;
#pragma unroll
      for (int jj = 0; jj < 4; jj++) {
        float p = __expf(pv[jj][r] - mnew);
        pv[jj][r] = p;
        rs += p;
      }
#pragma unroll
      for (int off = 8; off >= 1; off >>= 1) rs += __shfl_xor(rs, off, 64);
      lrun[r] = lrun[r] * scale + rs;
      mrun[r] = mnew;
#pragma unroll
      for (int s4 = 0; s4 < 4; s4++) acc[s4][r] *= scale;
    }
    // write P (bf16) to LDS in A-fragment layout
#pragma unroll
    for (int jj = 0; jj < 4; jj++)
#pragma unroll
      for (int r = 0; r < 4; r++) {
        bf16 pb = __float2bfloat16(pv[jj][r]);
        Pw[(lg * 4 + r) * PPAD + jj * 16 + lr] = *reinterpret_cast<short*>(&pb);
      }
    __syncthreads();

    // O += P V
    bf16x8s pa0 = *reinterpret_cast<const bf16x8s*>(&Pw[lr * PPAD + lk]);
    bf16x8s pa1 = *reinterpret_cast<const bf16x8s*>(&Pw[lr * PPAD + 32 + lk]);
#pragma unroll
    for (int s4 = 0; s4 < 4; s4++) {
      bf16x8s v0 = *reinterpret_cast<const bf16x8s*>(
          &Vts[(s4 * 16 + lr) * 64 + ((0 + lg) ^ swz) * 8]);
      bf16x8s v1 = *reinterpret_cast<const bf16x8s*>(
          &Vts[(s4 * 16 + lr) * 64 + ((4 + lg) ^ swz) * 8]);
      acc[s4] = __builtin_amdgcn_mfma_f32_16x16x32_bf16(pa0, v0, acc[s4], 0, 0, 0);
      acc[s4] = __builtin_amdgcn_mfma_f32_16x16x32_bf16(pa1, v1, acc[s4], 0, 0, 0);
    }
  }

  // epilogue: normalize and store attention output (bf16)
#pragma unroll
  for (int s4 = 0; s4 < 4; s4++)
#pragma unroll
    for (int r = 0; r < 4; r++) {
      size_t row = (size_t)(b * NN + q0 + w * 16 + lg * 4 + r);
      float v = acc[s4][r] / lrun[r];
      Ob[row * DD + h * 64 + s4 * 16 + lr] = __float2bfloat16(v);
    }
}

// ---------------- orchestration ----------------
extern "C" void kernel_launch(void* const* d_in, const int* in_sizes, int n_in,
                              void* d_out, int out_size, void* d_ws, size_t ws_size,
                              hipStream_t stream) {
  (void)in_sizes; (void)n_in; (void)out_size; (void)ws_size;
  const float* x    = (const float*)d_in[0];
  const float* cg   = (const float*)d_in[1];
  const float* mask = (const float*)d_in[2];
  const float* Wq   = (const float*)d_in[3];
  const float* bq   = (const float*)d_in[4];
  const float* Wk   = (const float*)d_in[5];
  const float* bk   = (const float*)d_in[6];
  const float* Wc   = (const float*)d_in[7];
  const float* bc   = (const float*)d_in[8];
  const float* We   = (const float*)d_in[9];
  const float* be   = (const float*)d_in[10];
  const float* Wv   = (const float*)d_in[11];
  const float* bv   = (const float*)d_in[12];
  const float* Wo   = (const float*)d_in[13];
  const float* bo   = (const float*)d_in[14];

  auto MB = [](size_t m) { return m << 20; };
  char* ws = (char*)d_ws;
  bf16* xb   = (bf16*)(ws + MB(0));    // 16 MB
  bf16* WqT  = (bf16*)(ws + MB(16));   // 2 MB each
  bf16* WkT  = (bf16*)(ws + MB(18));
  bf16* WvT  = (bf16*)(ws + MB(20));
  bf16* WoT  = (bf16*)(ws + MB(22));
  float* cq  = (float*)(ws + MB(24));  // 8 MB f32
  float* ck  = (float*)(ws + MB(32));  // 8 MB f32
  bf16* Qb   = (bf16*)(ws + MB(40));   // 16 MB
  bf16* Kb   = (bf16*)(ws + MB(56));   // 16 MB
  bf16* Vb   = (bf16*)(ws + MB(72));   // 16 MB (dead after transpose_v)
  bf16* Vt   = (bf16*)(ws + MB(88));   // 16 MB -> peak 104 MB
  bf16* Ob   = (bf16*)(ws + MB(72));   // overlays Vb (dead)
  // overlays, dead after cq/ck GEMMs (before Qb/Kb are written):
  bf16* WcT  = (bf16*)(ws + MB(40));   // 4 MB
  bf16* WeT  = (bf16*)(ws + MB(44));   // 4 MB
  bf16* cgb  = (bf16*)(ws + MB(48));   // 8 MB
  bf16* cgT  = (bf16*)(ws + MB(56));   // 8 MB

  cast_f32_bf16<<<dim3(BB * NN * DD / 4 / 256), 256, 0, stream>>>(x, xb, BB * NN * DD);
  cast_f32_bf16<<<dim3(NN * NN / 4 / 256), 256, 0, stream>>>(cg, cgb, NN * NN);
  dim3 tb(32, 8);
  transpose_cast<<<dim3(DD / 32, DD / 32), tb, 0, stream>>>(Wq, WqT, DD, DD);
  transpose_cast<<<dim3(DD / 32, DD / 32), tb, 0, stream>>>(Wk, WkT, DD, DD);
  transpose_cast<<<dim3(DD / 32, DD / 32), tb, 0, stream>>>(Wv, WvT, DD, DD);
  transpose_cast<<<dim3(DD / 32, DD / 32), tb, 0, stream>>>(Wo, WoT, DD, DD);
  transpose_cast<<<dim3(DD / 32, NN / 32), tb, 0, stream>>>(Wc, WcT, NN, DD);
  transpose_cast<<<dim3(DD / 32, NN / 32), tb, 0, stream>>>(We, WeT, NN, DD);
  transpose_cast<<<dim3(NN / 32, NN / 32), tb, 0, stream>>>(cg, cgT, NN, NN);

  // cq = cg@Wc + bc ; ck = cg^T@We + be   (f32 out)
  gemm_bt<0, 0><<<dim3(DD / 128, NN / 128), 256, 0, stream>>>(cgb, WcT, cq, bc, nullptr, NN, DD, NN, 1.0f);
  gemm_bt<0, 0><<<dim3(DD / 128, NN / 128), 256, 0, stream>>>(cgT, WeT, ck, be, nullptr, NN, DD, NN, 1.0f);
  // Q = 0.125*(x@Wq + bq + cq[row]) ; K = x@Wk + bk + ck[row] ; V = x@Wv + bv   (bf16 out)
  gemm_bt<1, 1><<<dim3(DD / 128, BB * NN / 128), 256, 0, stream>>>(xb, WqT, Qb, bq, cq, BB * NN, DD, DD, 0.125f);
  gemm_bt<1, 1><<<dim3(DD / 128, BB * NN / 128), 256, 0, stream>>>(xb, WkT, Kb, bk, ck, BB * NN, DD, DD, 1.0f);
  gemm_bt<1, 0><<<dim3(DD / 128, BB * NN / 128), 256, 0, stream>>>(xb, WvT, Vb, bv, nullptr, BB * NN, DD, DD, 1.0f);

  transpose_v<<<dim3(NN / 32, 2, BB * HH), tb, 0, stream>>>(Vb, Vt);

  attn_k<<<dim3(NN / 64, HH, BB), 256, 0, stream>>>(Qb, Kb, Vt, mask, Ob);

  // out = attn@Wo + bo  (f32 out)
  gemm_bt<0, 0><<<dim3(DD / 128, BB * NN / 128), 256, 0, stream>>>(Ob, WoT, (float*)d_out, bo, nullptr, BB * NN, DD, DD, 1.0f);
}